// Round 1
// baseline (1405.238 us; speedup 1.0000x reference)
//
#include <hip/hip_runtime.h>
#include <hip/hip_bf16.h>
#include <cstdint>
#include <cstddef>

// ---------------- problem constants ----------------
#define B_    8
#define S_    1500
#define D_    1024
#define H_    16
#define HD_   64
#define DFF_  4096
#define M_    12000   // B_*S_

typedef __bf16 bf16;
typedef __attribute__((ext_vector_type(8))) __bf16 bf16x8;
typedef __attribute__((ext_vector_type(4))) float f32x4;

#define MFMA16(a, b, c) __builtin_amdgcn_mfma_f32_16x16x32_bf16((a), (b), (c), 0, 0, 0)

// async global->LDS, 16B per lane. LDS dest must be wave-uniform base + lane*16
// (our staging index t*8 elems satisfies this per-wave).
static __device__ __forceinline__ void gload16(const void* g, void* l) {
  __builtin_amdgcn_global_load_lds(
      (const __attribute__((address_space(1))) void*)(uintptr_t)g,
      (__attribute__((address_space(3))) void*)(uintptr_t)l, 16, 0, 0);
}

// ---------------- workspace layout (bytes) ----------------
static constexpr size_t WQ_OFF  = 0;
static constexpr size_t WK_OFF  = WQ_OFF + (size_t)D_ * D_ * 2;
static constexpr size_t WV_OFF  = WK_OFF + (size_t)D_ * D_ * 2;
static constexpr size_t WO_OFF  = WV_OFF + (size_t)D_ * D_ * 2;
static constexpr size_t W1_OFF  = WO_OFF + (size_t)D_ * D_ * 2;
static constexpr size_t W2_OFF  = W1_OFF + (size_t)DFF_ * D_ * 2;
static constexpr size_t H_OFF   = W2_OFF + (size_t)DFF_ * D_ * 2;  // h -> ctx -> act-chunk
static constexpr size_t HREG_SZ = (size_t)3072 * DFF_ * 2;          // 25,165,824 (act chunk max)
static constexpr size_t Q_OFF   = H_OFF + HREG_SZ;
static constexpr size_t K_OFF   = Q_OFF + (size_t)M_ * D_ * 2;
static constexpr size_t V_OFF   = K_OFF + (size_t)M_ * D_ * 2;
static constexpr size_t X2_OFF  = Q_OFF;   // fp32 x2 overlays q+k (exactly 49,152,000 B)
static constexpr size_t H2_OFF  = V_OFF;   // h2 overlays v
static constexpr size_t ACT_OFF = H_OFF;   // act chunk overlays h/ctx

// ---------------- fp32 -> bf16 convert ----------------
__launch_bounds__(256)
__global__ void cvt_bf16(const float* __restrict__ src, bf16* __restrict__ dst, int n) {
  int i = (blockIdx.x * 256 + threadIdx.x) * 4;
  if (i < n) {
    float4 f = *(const float4*)(src + i);
    dst[i + 0] = (bf16)f.x;
    dst[i + 1] = (bf16)f.y;
    dst[i + 2] = (bf16)f.z;
    dst[i + 3] = (bf16)f.w;
  }
}

// ---------------- fused LayerNorm (fp32 in, bf16 out), one block per row ----------------
__launch_bounds__(256)
__global__ void ln_fused(const float* __restrict__ x, const float* __restrict__ g,
                         const float* __restrict__ bb, bf16* __restrict__ out) {
  const int row = blockIdx.x;
  const int t = threadIdx.x;
  const float4 xv = *(const float4*)(x + (size_t)row * D_ + t * 4);
  float s  = xv.x + xv.y + xv.z + xv.w;
  float s2 = xv.x * xv.x + xv.y * xv.y + xv.z * xv.z + xv.w * xv.w;
#pragma unroll
  for (int m = 32; m >= 1; m >>= 1) {
    s  += __shfl_xor(s, m);
    s2 += __shfl_xor(s2, m);
  }
  __shared__ float red[8];
  const int w = t >> 6;
  if ((t & 63) == 0) { red[w] = s; red[4 + w] = s2; }
  __syncthreads();
  s  = red[0] + red[1] + red[2] + red[3];
  s2 = red[4] + red[5] + red[6] + red[7];
  const float mu  = s * (1.0f / D_);
  const float var = s2 * (1.0f / D_) - mu * mu;
  const float rs  = rsqrtf(var + 1e-5f);
  const float4 gv = *(const float4*)(g + t * 4);
  const float4 bv = *(const float4*)(bb + t * 4);
  bf16* o = out + (size_t)row * D_ + t * 4;
  o[0] = (bf16)((xv.x - mu) * rs * gv.x + bv.x);
  o[1] = (bf16)((xv.y - mu) * rs * gv.y + bv.y);
  o[2] = (bf16)((xv.z - mu) * rs * gv.z + bv.z);
  o[3] = (bf16)((xv.w - mu) * rs * gv.w + bv.w);
}

// ---------------- GEMM: C[m][n] = sum_k A[m][k] * W[n][k]  (both K-contiguous) ----------------
// 128x128 tile, BK=64, 256 threads (4 waves, 2x2), 16x16x32 bf16 MFMA (m97 structure).
// EPI: 0 = store bf16; 1 = store bf16 * scale; 2 = bias + exact GELU -> bf16;
//      3 = (+bias) + resid -> fp32
template <int EPI>
__launch_bounds__(256)
__global__ void gemm_bt(const bf16* __restrict__ A, const bf16* __restrict__ Bw,
                        int M, int N, int K,
                        bf16* __restrict__ outB, float* __restrict__ outF,
                        const float* __restrict__ bias, const float* __restrict__ resid,
                        float scale) {
  __shared__ bf16 a_lds[128 * 64];
  __shared__ bf16 b_lds[128 * 64];
  const int t = threadIdx.x;
  const int lane = t & 63, wid = t >> 6;
  const int wr = wid >> 1, wc = wid & 1;
  const int mrow0 = blockIdx.x * 128;
  const int ncol0 = blockIdx.y * 128;
  const int l15 = lane & 15;
  const int khi = (lane >> 4) << 3;

  f32x4 acc[4][4] = {};

  for (int k0 = 0; k0 < K; k0 += 64) {
#pragma unroll
    for (int i = 0; i < 4; ++i) {  // A tile 128x64
      int idx = i * 2048 + t * 8;
      int row = idx >> 6, col = idx & 63;
      int gr = mrow0 + row;
      gr = gr < M ? gr : M - 1;
      gload16(A + (size_t)gr * K + (k0 + col), (char*)a_lds + idx * 2);
    }
#pragma unroll
    for (int i = 0; i < 4; ++i) {  // B tile 128x64 (N always multiple of 128)
      int idx = i * 2048 + t * 8;
      int row = idx >> 6, col = idx & 63;
      gload16(Bw + (size_t)(ncol0 + row) * K + (k0 + col), (char*)b_lds + idx * 2);
    }
    __syncthreads();
#pragma unroll
    for (int kk = 0; kk < 2; ++kk) {
      bf16x8 af[4], bfv[4];
#pragma unroll
      for (int m = 0; m < 4; ++m)
        af[m] = *(const bf16x8*)&a_lds[(wr * 64 + m * 16 + l15) * 64 + kk * 32 + khi];
#pragma unroll
      for (int n = 0; n < 4; ++n)
        bfv[n] = *(const bf16x8*)&b_lds[(wc * 64 + n * 16 + l15) * 64 + kk * 32 + khi];
#pragma unroll
      for (int m = 0; m < 4; ++m)
#pragma unroll
        for (int n = 0; n < 4; ++n)
          acc[m][n] = MFMA16(af[m], bfv[n], acc[m][n]);
    }
    __syncthreads();
  }

  const int r0 = (lane >> 4) << 2;
#pragma unroll
  for (int m = 0; m < 4; ++m) {
#pragma unroll
    for (int n = 0; n < 4; ++n) {
      int col = ncol0 + wc * 64 + n * 16 + l15;
#pragma unroll
      for (int r = 0; r < 4; ++r) {
        int row = mrow0 + wr * 64 + m * 16 + r0 + r;
        if (row < M) {
          float v = acc[m][n][r];
          if constexpr (EPI == 1) v *= scale;
          if constexpr (EPI == 2) {
            float xg = v + bias[col];
            v = 0.5f * xg * (1.0f + erff(xg * 0.70710678118654752f));
          }
          if constexpr (EPI == 3) {
            v += resid[(size_t)row * N + col];
            if (bias) v += bias[col];
            outF[(size_t)row * N + col] = v;
          } else {
            outB[(size_t)row * N + col] = (bf16)v;
          }
        }
      }
    }
  }
}

// ---------------- flash attention fwd (non-causal), bf16 in/out ----------------
// grid: (ceil(S/64), B*H); block 256 = 4 waves; wave w owns 16 q-rows.
__launch_bounds__(256)
__global__ void attn_fwd(const bf16* __restrict__ q, const bf16* __restrict__ k,
                         const bf16* __restrict__ v, bf16* __restrict__ cx) {
  __shared__ bf16 k_lds[64 * 64];   // [key][d]
  __shared__ bf16 vt_lds[64 * 64];  // [d][key]
  __shared__ bf16 p_lds[4][16 * 64];

  const int t = threadIdx.x;
  const int lane = t & 63, w = t >> 6;
  const int qt = blockIdx.x;
  const int bh = blockIdx.y;
  const int b = bh >> 4, h = bh & 15;
  const int l15 = lane & 15;
  const int khi = (lane >> 4) << 3;

  const size_t headoff = ((size_t)b * S_) * D_ + (size_t)h * HD_;
  const bf16* qh = q + headoff;
  const bf16* kh = k + headoff;
  const bf16* vh = v + headoff;

  // hoist Q fragments (A-operand layout: row = lane%16, k = (lane/16)*8 ..)
  int qr = qt * 64 + w * 16 + l15;
  int qrc = qr < S_ ? qr : S_ - 1;
  bf16x8 qf[2];
  qf[0] = *(const bf16x8*)(qh + (size_t)qrc * D_ + khi);
  qf[1] = *(const bf16x8*)(qh + (size_t)qrc * D_ + 32 + khi);

  f32x4 oacc[4] = {};
  float mrun[4] = {-1e30f, -1e30f, -1e30f, -1e30f};
  float lrun[4] = {0.f, 0.f, 0.f, 0.f};

  const int NT = (S_ + 63) / 64;  // 24
  for (int kt = 0; kt < NT; ++kt) {
    // stage K tile [64 keys][64 d]
#pragma unroll
    for (int i = 0; i < 2; ++i) {
      int idx = i * 2048 + t * 8;
      int key = idx >> 6, d = idx & 63;
      int gk = kt * 64 + key;
      gk = gk < S_ ? gk : S_ - 1;
      gload16(kh + (size_t)gk * D_ + d, (char*)k_lds + idx * 2);
    }
    // stage V^T tile [64 d][64 keys]
#pragma unroll
    for (int i = 0; i < 2; ++i) {
      int idx = i * 2048 + t * 8;
      int key = idx >> 6, d0 = idx & 63;
      int gk = kt * 64 + key;
      gk = gk < S_ ? gk : S_ - 1;
      bf16x8 vv = *(const bf16x8*)(vh + (size_t)gk * D_ + d0);
#pragma unroll
      for (int j = 0; j < 8; ++j) vt_lds[(d0 + j) * 64 + key] = vv[j];
    }
    __syncthreads();

    // S = Q K^T  (16 x 64 per wave)
    f32x4 sa[4];
#pragma unroll
    for (int nb = 0; nb < 4; ++nb) {
      f32x4 z = {};
      z = MFMA16(qf[0], *(const bf16x8*)&k_lds[(nb * 16 + l15) * 64 + khi], z);
      z = MFMA16(qf[1], *(const bf16x8*)&k_lds[(nb * 16 + l15) * 64 + 32 + khi], z);
      sa[nb] = z;
    }

    // mask + online softmax (rows r: (lane>>4)*4 + r, col: nb*16 + lane%16)
    float pv[4][4];
#pragma unroll
    for (int nb = 0; nb < 4; ++nb) {
      int col = kt * 64 + nb * 16 + l15;
      bool cvld = col < S_;
#pragma unroll
      for (int r = 0; r < 4; ++r) pv[nb][r] = cvld ? sa[nb][r] : -1e30f;
    }
#pragma unroll
    for (int r = 0; r < 4; ++r) {
      float mx = fmaxf(fmaxf(pv[0][r], pv[1][r]), fmaxf(pv[2][r], pv[3][r]));
      mx = fmaxf(mx, __shfl_xor(mx, 1));
      mx = fmaxf(mx, __shfl_xor(mx, 2));
      mx = fmaxf(mx, __shfl_xor(mx, 4));
      mx = fmaxf(mx, __shfl_xor(mx, 8));
      float mnew = fmaxf(mrun[r], mx);
      float corr = __expf(mrun[r] - mnew);
      float ps = 0.f;
#pragma unroll
      for (int nb = 0; nb < 4; ++nb) {
        float p = __expf(pv[nb][r] - mnew);
        pv[nb][r] = p;
        ps += p;
      }
      ps += __shfl_xor(ps, 1);
      ps += __shfl_xor(ps, 2);
      ps += __shfl_xor(ps, 4);
      ps += __shfl_xor(ps, 8);
      lrun[r] = lrun[r] * corr + ps;
      mrun[r] = mnew;
#pragma unroll
      for (int db = 0; db < 4; ++db) oacc[db][r] *= corr;
    }

    // P -> per-wave LDS (C-layout write, A-layout read)
#pragma unroll
    for (int nb = 0; nb < 4; ++nb)
#pragma unroll
      for (int r = 0; r < 4; ++r)
        p_lds[w][((lane >> 4) * 4 + r) * 64 + nb * 16 + l15] = (bf16)pv[nb][r];

    // ctx += P @ V
#pragma unroll
    for (int kk = 0; kk < 2; ++kk) {
      bf16x8 pf = *(const bf16x8*)&p_lds[w][l15 * 64 + kk * 32 + khi];
#pragma unroll
      for (int db = 0; db < 4; ++db) {
        bf16x8 vf = *(const bf16x8*)&vt_lds[(db * 16 + l15) * 64 + kk * 32 + khi];
        oacc[db] = MFMA16(pf, vf, oacc[db]);
      }
    }
    __syncthreads();
  }

  // normalize + store
#pragma unroll
  for (int r = 0; r < 4; ++r) {
    int qrow = qt * 64 + w * 16 + (lane >> 4) * 4 + r;
    if (qrow < S_) {
      float inv = 1.0f / lrun[r];
#pragma unroll
      for (int db = 0; db < 4; ++db)
        cx[headoff + (size_t)qrow * D_ + db * 16 + l15] = (bf16)(oacc[db][r] * inv);
    }
  }
}

// ---------------- launch ----------------
extern "C" void kernel_launch(void* const* d_in, const int* in_sizes, int n_in,
                              void* d_out, int out_size, void* d_ws, size_t ws_size,
                              hipStream_t stream) {
  const float* x   = (const float*)d_in[0];
  const float* Wq  = (const float*)d_in[1];
  const float* Wk  = (const float*)d_in[2];
  const float* Wv  = (const float*)d_in[3];
  const float* Wo  = (const float*)d_in[4];
  const float* W1  = (const float*)d_in[5];
  const float* b1  = (const float*)d_in[6];
  const float* W2  = (const float*)d_in[7];
  const float* b2  = (const float*)d_in[8];
  const float* g1  = (const float*)d_in[9];
  const float* be1 = (const float*)d_in[10];
  const float* g2  = (const float*)d_in[11];
  const float* be2 = (const float*)d_in[12];
  float* out = (float*)d_out;

  char* ws = (char*)d_ws;
  bf16* wq_b  = (bf16*)(ws + WQ_OFF);
  bf16* wk_b  = (bf16*)(ws + WK_OFF);
  bf16* wv_b  = (bf16*)(ws + WV_OFF);
  bf16* wo_b  = (bf16*)(ws + WO_OFF);
  bf16* w1_b  = (bf16*)(ws + W1_OFF);
  bf16* w2_b  = (bf16*)(ws + W2_OFF);
  bf16* h_b   = (bf16*)(ws + H_OFF);
  bf16* q_b   = (bf16*)(ws + Q_OFF);
  bf16* k_b   = (bf16*)(ws + K_OFF);
  bf16* v_b   = (bf16*)(ws + V_OFF);
  float* x2   = (float*)(ws + X2_OFF);
  bf16* h2_b  = (bf16*)(ws + H2_OFF);
  bf16* act_b = (bf16*)(ws + ACT_OFF);
  bf16* ctx_b = h_b;  // ctx overlays h

  // weight converts
  cvt_bf16<<<(D_ * D_) / 1024, 256, 0, stream>>>(Wq, wq_b, D_ * D_);
  cvt_bf16<<<(D_ * D_) / 1024, 256, 0, stream>>>(Wk, wk_b, D_ * D_);
  cvt_bf16<<<(D_ * D_) / 1024, 256, 0, stream>>>(Wv, wv_b, D_ * D_);
  cvt_bf16<<<(D_ * D_) / 1024, 256, 0, stream>>>(Wo, wo_b, D_ * D_);
  cvt_bf16<<<(DFF_ * D_) / 1024, 256, 0, stream>>>(W1, w1_b, DFF_ * D_);
  cvt_bf16<<<(DFF_ * D_) / 1024, 256, 0, stream>>>(W2, w2_b, DFF_ * D_);

  // LN1
  ln_fused<<<M_, 256, 0, stream>>>(x, g1, be1, h_b);

  // QKV projections
  dim3 gqkv((M_ + 127) / 128, D_ / 128);
  gemm_bt<1><<<gqkv, 256, 0, stream>>>(h_b, wq_b, M_, D_, D_, q_b, nullptr, nullptr, nullptr, 0.125f);
  gemm_bt<0><<<gqkv, 256, 0, stream>>>(h_b, wk_b, M_, D_, D_, k_b, nullptr, nullptr, nullptr, 0.f);
  gemm_bt<0><<<gqkv, 256, 0, stream>>>(h_b, wv_b, M_, D_, D_, v_b, nullptr, nullptr, nullptr, 0.f);

  // attention (writes ctx into h region; h dead after QKV)
  attn_fwd<<<dim3((S_ + 63) / 64, B_ * H_), 256, 0, stream>>>(q_b, k_b, v_b, ctx_b);

  // x2 = x + ctx @ Wo^T   (x2 overlays q+k; q/k dead)
  gemm_bt<3><<<gqkv, 256, 0, stream>>>(ctx_b, wo_b, M_, D_, D_, nullptr, x2, nullptr, x, 0.f);

  // LN2 (h2 overlays v; v dead)
  ln_fused<<<M_, 256, 0, stream>>>(x2, g2, be2, h2_b);

  // FFN in 4 row-chunks of 3072 (act chunk overlays h/ctx; ctx dead)
  for (int c = 0; c < 4; ++c) {
    int r0c = c * 3072;
    int nr = M_ - r0c;
    if (nr > 3072) nr = 3072;
    int mt = (nr + 127) / 128;
    gemm_bt<2><<<dim3(mt, DFF_ / 128), 256, 0, stream>>>(
        h2_b + (size_t)r0c * D_, w1_b, nr, DFF_, D_, act_b, nullptr, b1, nullptr, 0.f);
    gemm_bt<3><<<dim3(mt, D_ / 128), 256, 0, stream>>>(
        act_b, w2_b, nr, D_, DFF_, nullptr, out + (size_t)r0c * D_, b2,
        x2 + (size_t)r0c * D_, 0.f);
  }
}